// Round 1
// baseline (642.564 us; speedup 1.0000x reference)
//
#include <hip/hip_runtime.h>

#define CIN 16
#define COUT 16
#define S 24
#define PLANE (S*S)            // 576
#define CISTRIDE (S*S*S*S)     // 331776 floats per (n,ci)
#define LROW 26
#define LPLANE (LROW*LROW)     // 676

__global__ __launch_bounds__(192, 2)
void conv4d_kernel(const float* __restrict__ in, const float* __restrict__ wgt,
                   const float* __restrict__ bias, float* __restrict__ out) {
    // zero-padded input slab: [ci][26][26]; border stays 0 forever
    __shared__ float lds[CIN * LPLANE]; // 43264 B

    const int t  = threadIdx.x;
    const int b  = blockIdx.x;
    const int n  = b / (S * S);
    const int uv = b % (S * S);
    const int u  = uv / S;
    const int v  = uv % S;

    for (int i = t; i < CIN * LPLANE; i += 192) lds[i] = 0.0f;

    // 3 output (h,w) positions per thread
    const int p0 = t, p1 = t + 192, p2 = t + 384;
    const int h0 = p0 / S, w0 = p0 % S;
    const int h1 = p1 / S, w1 = p1 % S;
    const int h2 = p2 / S, w2 = p2 % S;

    float acc0[COUT], acc1[COUT], acc2[COUT];
    #pragma unroll
    for (int co = 0; co < COUT; ++co) { acc0[co] = 0.f; acc1[co] = 0.f; acc2[co] = 0.f; }

    const float* in_n = in + (size_t)n * CIN * CISTRIDE;

    for (int ku = 0; ku < 3; ++ku) {
        const int uu = u + ku - 1;
        if (uu < 0 || uu >= S) continue;           // block-uniform
        for (int kv = 0; kv < 3; ++kv) {
            const int vv = v + kv - 1;
            if (vv < 0 || vv >= S) continue;       // block-uniform

            __syncthreads();                        // protect lds from prior readers
            // stage in[n, :, uu, vv, :, :] -> lds interior (coalesced float4)
            const float* src = in_n + (uu * S + vv) * PLANE;
            #pragma unroll
            for (int j = 0; j < 12; ++j) {
                const int idx = t + j * 192;        // 0..2303 float4s
                const int ci  = idx / 144;
                const int r   = idx % 144;          // float4 within 24x24 plane
                const float4 val = *reinterpret_cast<const float4*>(src + ci * CISTRIDE + r * 4);
                const int hh = r / 6;               // (r*4)/24
                const int ww = (r % 6) * 4;         // (r*4)%24
                float* dst = &lds[ci * LPLANE + (hh + 1) * LROW + (ww + 1)];
                dst[0] = val.x; dst[1] = val.y; dst[2] = val.z; dst[3] = val.w;
            }
            __syncthreads();

            const float* wkk = wgt + ku * 27 + kv * 9;
            for (int ci = 0; ci < CIN; ++ci) {
                const float* lci = &lds[ci * LPLANE];
                const float* wci = wkk + ci * 81;
                #pragma unroll
                for (int kh = 0; kh < 3; ++kh) {
                    #pragma unroll
                    for (int kw = 0; kw < 3; ++kw) {
                        const float x0 = lci[(h0 + kh) * LROW + (w0 + kw)];
                        const float x1 = lci[(h1 + kh) * LROW + (w1 + kw)];
                        const float x2 = lci[(h2 + kh) * LROW + (w2 + kw)];
                        const float* wp = wci + kh * 3 + kw;
                        #pragma unroll
                        for (int co = 0; co < COUT; ++co) {
                            const float wv = wp[co * 1296];   // uniform addr -> s_load
                            acc0[co] = fmaf(x0, wv, acc0[co]);
                            acc1[co] = fmaf(x1, wv, acc1[co]);
                            acc2[co] = fmaf(x2, wv, acc2[co]);
                        }
                    }
                }
            }
        }
    }

    float* out_n = out + (size_t)n * COUT * CISTRIDE + (size_t)(u * S + v) * PLANE;
    #pragma unroll
    for (int co = 0; co < COUT; ++co) {
        const float bv = bias[co];
        out_n[co * CISTRIDE + p0] = acc0[co] + bv;
        out_n[co * CISTRIDE + p1] = acc1[co] + bv;
        out_n[co * CISTRIDE + p2] = acc2[co] + bv;
    }
}

extern "C" void kernel_launch(void* const* d_in, const int* in_sizes, int n_in,
                              void* d_out, int out_size, void* d_ws, size_t ws_size,
                              hipStream_t stream) {
    const float* in   = (const float*)d_in[0];
    const float* wgt  = (const float*)d_in[1];
    const float* bias = (const float*)d_in[2];
    float* out        = (float*)d_out;
    conv4d_kernel<<<dim3(2 * S * S), dim3(192), 0, stream>>>(in, wgt, bias, out);
}

// Round 3
// 100.139 us; speedup vs baseline: 6.4167x; 6.4167x over previous
//
#include <hip/hip_runtime.h>

#define CIN 16
#define COUT 16
#define S 24
#define PLANE 576
#define CISTRIDE 331776          // floats per (n,ci)
#define LROW 26

typedef __attribute__((ext_vector_type(8))) short bf16x8;
typedef __attribute__((ext_vector_type(4))) float f32x4;

#define HALF_B (26*26*8*2 + 16)          // 10832 B per ci-half (8 bf16/pos), +16B pad
#define SLAB_B (2*HALF_B)                // 21664
#define A_BASE SLAB_B                    // A-fragment buffer: 5 steps * 64 lanes * 16B
#define LDS_BYTES (SLAB_B + 5*64*16)     // 26784

__device__ inline ushort f2bf(float f) {            // round-to-nearest-even
    unsigned int u = __builtin_bit_cast(unsigned int, f);
    unsigned int r = u + 0x7fffu + ((u >> 16) & 1u);
    return (ushort)(r >> 16);
}

__global__ void __launch_bounds__(256)
conv4d_mfma(const float* __restrict__ in, const float* __restrict__ wgt,
            const float* __restrict__ bias, float* __restrict__ out) {
    __shared__ __align__(16) char lds[LDS_BYTES];
    ushort* lds16 = (ushort*)lds;

    const int t    = threadIdx.x;
    const int lane = t & 63;
    const int wv   = t >> 6;                 // wave id 0..3
    const int b    = blockIdx.x;
    const int nb   = b / PLANE;
    const int uv   = b % PLANE;
    const int u    = uv / S, v = uv % S;

    // B-fragment lane constants: n = lane&15 -> (dh,dw) in 4x4 tile;
    // group g = lane>>4: bit0 = ci-half, bit1 = offset parity
    const int n16 = lane & 15;
    const int dh = n16 >> 2, dw = n16 & 3;
    const int g  = lane >> 4;
    const int halfsel = g & 1;
    const int osel    = g >> 1;

    int laneBK[5];
    #pragma unroll
    for (int s = 0; s < 5; ++s) {
        int o = 2 * s + osel; if (o > 8) o = 8;   // clamped tail reads junk; A is zero there
        int kh = o / 3, kw = o % 3;
        laneBK[s] = halfsel * HALF_B + ((dh + kh) * LROW + (dw + kw)) * 16;
    }

    // zero slab (borders must stay zero; interior rewritten per tap)
    for (int i = t; i < SLAB_B / 4; i += 256) ((unsigned int*)lds)[i] = 0u;

    f32x4 acc[9];
    #pragma unroll
    for (int i = 0; i < 9; ++i) acc[i] = (f32x4){0.f, 0.f, 0.f, 0.f};

    const float* in_n = in + (size_t)nb * CIN * CISTRIDE;

    // weight repack ownership: thread = (co, ci)
    const int aco = t >> 4, aci = t & 15;
    const float* wthread = wgt + aco * 1296 + aci * 81;
    const int alane_lo = (aci >> 3) * 16 + aco;       // half=0 lane
    const int zidx = (4 * 64 + 32 + (t >> 3)) * 8 + (t & 7);  // A zero-pad slot

    __syncthreads();   // zeroed slab visible before first staging writes

    for (int ku = 0; ku < 3; ++ku) {
        const int uutap = u + ku - 1;
        if (uutap < 0 || uutap >= S) continue;        // block-uniform
        for (int kv = 0; kv < 3; ++kv) {
            const int vvtap = v + kv - 1;
            if (vvtap < 0 || vvtap >= S) continue;    // block-uniform
            const int tap = ku * 3 + kv;

            __syncthreads();  // previous tap's readers done

            // ---- stage A fragments: w[co][ci][tap*9 + o], o=0..8 ----
            {
                const float* wp = wthread + tap * 9;
                #pragma unroll
                for (int o = 0; o < 9; ++o) {
                    ushort hbits = f2bf(wp[o]);
                    int s = o >> 1, half = o & 1;
                    int alane = alane_lo + half * 32;
                    lds16[A_BASE / 2 + (s * 64 + alane) * 8 + (aci & 7)] = hbits;
                }
                lds16[A_BASE / 2 + zidx] = 0;  // zero K-tail (s=4, k>=16)
            }

            // ---- stage input slab as bf16 [half][pos][8ci] ----
            const float* src = in_n + (uutap * S + vvtap) * PLANE;
            #pragma unroll
            for (int rep = 0; rep < 3; ++rep) {
                int p = t + rep * 256;
                if (p < PLANE) {
                    int hh = p / S + 1, ww = p % S + 1;
                    float f[16];
                    #pragma unroll
                    for (int ci = 0; ci < 16; ++ci) f[ci] = src[(size_t)ci * CISTRIDE + p];
                    unsigned int pk[8];
                    #pragma unroll
                    for (int k = 0; k < 8; ++k)
                        pk[k] = (unsigned int)f2bf(f[2*k]) | ((unsigned int)f2bf(f[2*k+1]) << 16);
                    int q = hh * LROW + ww;
                    *(uint4*)(lds + 0 * HALF_B + q * 16) = make_uint4(pk[0], pk[1], pk[2], pk[3]);
                    *(uint4*)(lds + 1 * HALF_B + q * 16) = make_uint4(pk[4], pk[5], pk[6], pk[7]);
                }
            }
            __syncthreads();

            // ---- A fragments -> VGPRs (reused across 9 tiles) ----
            bf16x8 afr[5];
            #pragma unroll
            for (int s = 0; s < 5; ++s)
                afr[s] = *(const bf16x8*)(lds + A_BASE + (s * 64 + lane) * 16);

            // ---- GEMM: 9 tiles x 5 K-steps ----
            #pragma unroll
            for (int ti = 0; ti < 9; ++ti) {
                int tile = wv * 9 + ti;
                int tb = ((tile / 6) * 4 * LROW + (tile % 6) * 4) * 16;
                #pragma unroll
                for (int s = 0; s < 5; ++s) {
                    bf16x8 bfr = *(const bf16x8*)(lds + laneBK[s] + tb);
                    acc[ti] = __builtin_amdgcn_mfma_f32_16x16x32_bf16(afr[s], bfr, acc[ti], 0, 0, 0);
                }
            }
        }
    }

    // ---- epilogue: C frag col=lane&15 (position), row=g*4+reg (c_out) ----
    const int cobase = g * 4;
    float bv[4];
    #pragma unroll
    for (int r = 0; r < 4; ++r) bv[r] = bias[cobase + r];
    float* outp = out + (size_t)nb * COUT * CISTRIDE + (size_t)uv * PLANE;
    #pragma unroll
    for (int ti = 0; ti < 9; ++ti) {
        int tile = wv * 9 + ti;
        int h0 = (tile / 6) * 4, w0 = (tile % 6) * 4;
        int poff = (h0 + dh) * S + (w0 + dw);
        #pragma unroll
        for (int r = 0; r < 4; ++r)
            outp[(size_t)(cobase + r) * CISTRIDE + poff] = acc[ti][r] + bv[r];
    }
}

extern "C" void kernel_launch(void* const* d_in, const int* in_sizes, int n_in,
                              void* d_out, int out_size, void* d_ws, size_t ws_size,
                              hipStream_t stream) {
    const float* in   = (const float*)d_in[0];
    const float* wgt  = (const float*)d_in[1];
    const float* bias = (const float*)d_in[2];
    float* out        = (float*)d_out;
    conv4d_mfma<<<dim3(2 * PLANE), dim3(256), 0, stream>>>(in, wgt, bias, out);
}

// Round 4
// 96.663 us; speedup vs baseline: 6.6475x; 1.0360x over previous
//
#include <hip/hip_runtime.h>

#define S 24
#define PLANE 576
#define CISTRIDE 331776          // floats per (n,ci)
#define SLAB_POS 676             // 26*26 padded positions
#define SLAB_B 21632             // 676 * 32 B
#define CHUNKS 1352              // SLAB_B / 16
#define A_BYTES 46080            // 45 steps * 64 lanes * 16 B
#define WS_SLABS A_BYTES

typedef __attribute__((ext_vector_type(8))) short bf16x8;
typedef __attribute__((ext_vector_type(4))) float f32x4;

__device__ __forceinline__ ushort f2bf(float f) {   // round-to-nearest-even
    unsigned int u = __builtin_bit_cast(unsigned int, f);
    unsigned int r = u + 0x7fffu + ((u >> 16) & 1u);
    return (ushort)(r >> 16);
}

// ---------------- prepass 1: pack weight A-fragments into ws[0 .. A_BYTES) ----
// layout: [tap 0..8][s 0..4][lane 0..63] * 16B ; k_instep = g*8+j -> o=2s+(g>>1), ci=(g&1)*8+j
__global__ void pack_w(const float* __restrict__ wgt, char* __restrict__ ws) {
    for (int i = threadIdx.x; i < 2880; i += 256) {
        int step = i >> 6;            // 0..44
        int tap = step / 5, s = step % 5;
        int lane = i & 63;
        int co = lane & 15, gA = lane >> 4;
        int o = 2 * s + (gA >> 1);
        int cib = (gA & 1) * 8;
        ushort vals[8];
        #pragma unroll
        for (int j = 0; j < 8; ++j)
            vals[j] = (o <= 8) ? f2bf(wgt[co * 1296 + (cib + j) * 81 + tap * 9 + o]) : (ushort)0;
        uint4 pk;
        pk.x = vals[0] | ((unsigned)vals[1] << 16);
        pk.y = vals[2] | ((unsigned)vals[3] << 16);
        pk.z = vals[4] | ((unsigned)vals[5] << 16);
        pk.w = vals[6] | ((unsigned)vals[7] << 16);
        *(uint4*)(ws + (size_t)i * 16) = pk;
    }
}

// ---------------- prepass 2: transform each (n,u,v) slab to padded swizzled bf16
// storage index p = row*26 + (col ^ (row&1)); 32 B per position = 16 ci bf16
__global__ void pack_in(const float* __restrict__ in, char* __restrict__ ws) {
    int b = blockIdx.x;               // slab id = nb*576 + uv
    int nb = b / PLANE, uv = b % PLANE;
    const float* src = in + (size_t)nb * 16 * CISTRIDE + (size_t)uv * PLANE;
    char* dst = ws + WS_SLABS + (size_t)b * SLAB_B;
    for (int p = threadIdx.x; p < SLAB_POS; p += 256) {
        int row = p / 26, colswz = p % 26;
        int col = colswz ^ (row & 1);
        int hh = row - 1, ww = col - 1;
        uint4 lo, hi;
        if (hh >= 0 && hh < 24 && ww >= 0 && ww < 24) {
            int q = hh * 24 + ww;
            unsigned pk[8];
            #pragma unroll
            for (int k = 0; k < 8; ++k) {
                float a = src[(size_t)(2 * k) * CISTRIDE + q];
                float c = src[(size_t)(2 * k + 1) * CISTRIDE + q];
                pk[k] = (unsigned)f2bf(a) | ((unsigned)f2bf(c) << 16);
            }
            lo = make_uint4(pk[0], pk[1], pk[2], pk[3]);
            hi = make_uint4(pk[4], pk[5], pk[6], pk[7]);
        } else {
            lo = make_uint4(0, 0, 0, 0); hi = lo;
        }
        *(uint4*)(dst + (size_t)p * 32) = lo;
        *(uint4*)(dst + (size_t)p * 32 + 16) = hi;
    }
}

// ---------------- main kernel ----------------
__global__ void __launch_bounds__(256, 3)
conv4d_main(const char* __restrict__ ws, const float* __restrict__ bias,
            float* __restrict__ out) {
    __shared__ __align__(16) char lds[2 * SLAB_B];   // 43264 B double buffer

    const int t = threadIdx.x, lane = t & 63, wvid = t >> 6;
    const int b = blockIdx.x, nb = b / PLANE, uv = b % PLANE;
    const int u = uv / S, v = uv % S;
    const int n16 = lane & 15, g = lane >> 4;
    const int dh = n16 >> 2, dw = n16 & 3;
    const int half = g & 1, osel = g >> 1;

    // per-lane B read offsets (tap-independent); swizzle folded in
    int laneoff[5];
    #pragma unroll
    for (int s = 0; s < 5; ++s) {
        int o = 2 * s + osel; if (o > 8) o = 8;      // K-tail clamp (A is zero there)
        int kh = o / 3, kw = o % 3;
        int r = dh + kh;
        int c = (dw + kw) ^ (r & 1);
        laneoff[s] = (r * 26 + c) * 32 + half * 16;
    }
    const int wv_off = (wvid >> 1) * 9984 + (wvid & 1) * 384;  // wave's 3x3-tile quadrant

    f32x4 acc[9];
    #pragma unroll
    for (int i = 0; i < 9; ++i) acc[i] = (f32x4){0.f, 0.f, 0.f, 0.f};

    // valid tap mask
    unsigned mask = 0;
    #pragma unroll
    for (int ku = 0; ku < 3; ++ku) {
        int uu = u + ku - 1; if (uu < 0 || uu >= S) continue;
        #pragma unroll
        for (int kv = 0; kv < 3; ++kv) {
            int vv = v + kv - 1; if (vv < 0 || vv >= S) continue;
            mask |= 1u << (ku * 3 + kv);
        }
    }

    const char* slabs = ws + WS_SLABS;
    #define SLAB_PTR(tap) (slabs + ((size_t)nb * PLANE + (u + (tap) / 3 - 1) * S + (v + (tap) % 3 - 1)) * SLAB_B)

    #define STAGE(bufsel_, src_) do {                                              \
        const char* _s = (src_);                                                   \
        _Pragma("unroll")                                                          \
        for (int r2 = 0; r2 < 6; ++r2) {                                           \
            int chunk = r2 * 256 + t;                                              \
            if (r2 < 5 || t < 72)                                                  \
                __builtin_amdgcn_global_load_lds(                                  \
                    (const __attribute__((address_space(1))) unsigned int*)(_s + (size_t)chunk * 16), \
                    (__attribute__((address_space(3))) unsigned int*)(lds + (bufsel_) * SLAB_B + chunk * 16), \
                    16, 0, 0);                                                     \
        }                                                                          \
    } while (0)

    int cur = __ffs(mask) - 1;
    int bufsel = 0;
    STAGE(0, SLAB_PTR(cur));
    __syncthreads();

    while (1) {
        unsigned rem = mask >> (cur + 1);
        int nxt = rem ? (cur + 1 + __ffs(rem) - 1) : -1;
        if (nxt >= 0) STAGE(bufsel ^ 1, SLAB_PTR(nxt));   // overlaps with compute below

        // A fragments for current tap (L2-hot broadcast)
        bf16x8 afr[5];
        const char* ap = ws + (size_t)cur * 5120 + (size_t)lane * 16;
        #pragma unroll
        for (int s = 0; s < 5; ++s)
            afr[s] = *(const bf16x8*)(ap + s * 1024);

        const char* bp = lds + bufsel * SLAB_B + wv_off;
        #pragma unroll
        for (int ti = 0; ti < 9; ++ti) {
            const int timm = (ti / 3) * 3328 + (ti % 3) * 128;
            #pragma unroll
            for (int s = 0; s < 5; ++s) {
                bf16x8 bfr = *(const bf16x8*)(bp + timm + laneoff[s]);
                acc[ti] = __builtin_amdgcn_mfma_f32_16x16x32_bf16(afr[s], bfr, acc[ti], 0, 0, 0);
            }
        }
        __syncthreads();   // drains next-tap stage (issued before compute) + read/write fence
        if (nxt < 0) break;
        cur = nxt; bufsel ^= 1;
    }

    // epilogue: C col = lane&15 -> tile position (dh,dw); row = g*4+r -> c_out
    float bv[4];
    #pragma unroll
    for (int r = 0; r < 4; ++r) bv[r] = bias[g * 4 + r];
    float* outp = out + (size_t)nb * 16 * CISTRIDE + (size_t)uv * PLANE;
    #pragma unroll
    for (int ti = 0; ti < 9; ++ti) {
        int h0 = ((ti / 3) + (wvid >> 1) * 3) * 4;
        int w0 = ((ti % 3) + (wvid & 1) * 3) * 4;
        int pos = (h0 + dh) * S + (w0 + dw);
        #pragma unroll
        for (int r = 0; r < 4; ++r)
            outp[(size_t)(g * 4 + r) * CISTRIDE + pos] = acc[ti][r] + bv[r];
    }
}

extern "C" void kernel_launch(void* const* d_in, const int* in_sizes, int n_in,
                              void* d_out, int out_size, void* d_ws, size_t ws_size,
                              hipStream_t stream) {
    const float* in   = (const float*)d_in[0];
    const float* wgt  = (const float*)d_in[1];
    const float* bias = (const float*)d_in[2];
    float* out        = (float*)d_out;
    char* ws          = (char*)d_ws;

    pack_w<<<dim3(1), dim3(256), 0, stream>>>(wgt, ws);
    pack_in<<<dim3(2 * PLANE), dim3(256), 0, stream>>>(in, ws);
    conv4d_main<<<dim3(2 * PLANE), dim3(256), 0, stream>>>(ws, bias, out);
}

// Round 5
// 89.032 us; speedup vs baseline: 7.2172x; 1.0857x over previous
//
#include <hip/hip_runtime.h>

#define S 24
#define PLANE 576
#define CISTRIDE 331776          // floats per (n,ci)
#define SLAB_B 21632             // 676 positions * 32 B
#define A_BYTES 46080            // 9 taps * 5 steps * 64 lanes * 16 B
#define WS_SLABS A_BYTES

typedef __attribute__((ext_vector_type(8))) short bf16x8;
typedef __attribute__((ext_vector_type(4))) float f32x4;

__device__ __forceinline__ ushort f2bf(float f) {   // round-to-nearest-even
    unsigned int u = __builtin_bit_cast(unsigned int, f);
    unsigned int r = u + 0x7fffu + ((u >> 16) & 1u);
    return (ushort)(r >> 16);
}

// slot swizzle: byte offset for (row,col,half) = ((row*26+col)*32 + half*16) ^ ((row&3)<<4)
__device__ __forceinline__ int swz(int row, int col, int half) {
    return (((row * 26 + col) * 32) + half * 16) ^ ((row & 3) << 4);
}

// ---------------- prepass: pack input slabs (+ weights from block 0) ----------------
__global__ void pack_in(const float* __restrict__ in, const float* __restrict__ wgt,
                        char* __restrict__ ws) {
    const int b = blockIdx.x;            // 1152 slabs
    const int nb = b / PLANE, uv = b % PLANE;
    const float* src = in + (size_t)nb * 16 * CISTRIDE + (size_t)uv * PLANE;
    char* dst = ws + WS_SLABS + (size_t)b * SLAB_B;
    const int t = threadIdx.x;

    if (t < 144) {                       // 4 consecutive interior positions
        float4 f[16];
        #pragma unroll
        for (int ci = 0; ci < 16; ++ci)
            f[ci] = *(const float4*)(src + (size_t)ci * CISTRIDE + 4 * t);
        #pragma unroll
        for (int j = 0; j < 4; ++j) {
            int p = 4 * t + j;
            int row = p / 24 + 1, col = p % 24 + 1;
            unsigned pk[8];
            #pragma unroll
            for (int k = 0; k < 8; ++k) {
                float a = ((const float*)&f[2 * k])[j];
                float c = ((const float*)&f[2 * k + 1])[j];
                pk[k] = (unsigned)f2bf(a) | ((unsigned)f2bf(c) << 16);
            }
            *(uint4*)(dst + swz(row, col, 0)) = make_uint4(pk[0], pk[1], pk[2], pk[3]);
            *(uint4*)(dst + swz(row, col, 1)) = make_uint4(pk[4], pk[5], pk[6], pk[7]);
        }
    } else if (t < 244) {                // 100 border positions -> zeros
        int idx = t - 144, row, col;
        if (idx < 26)      { row = 0;        col = idx; }
        else if (idx < 52) { row = 25;       col = idx - 26; }
        else if (idx < 76) { row = idx - 51; col = 0; }
        else               { row = idx - 75; col = 25; }
        uint4 z = make_uint4(0, 0, 0, 0);
        *(uint4*)(dst + swz(row, col, 0)) = z;
        *(uint4*)(dst + swz(row, col, 1)) = z;
    }

    if (b == 0) {                        // weight A-fragments -> ws[0..A_BYTES)
        for (int i = t; i < 2880; i += 256) {
            int step = i >> 6;           // 0..44
            int tap = step / 5, s = step % 5;
            int lane = i & 63;
            int co = lane & 15, gA = lane >> 4;
            int o = 2 * s + (gA >> 1);
            int cib = (gA & 1) * 8;
            ushort vals[8];
            #pragma unroll
            for (int j = 0; j < 8; ++j)
                vals[j] = (o <= 8) ? f2bf(wgt[co * 1296 + (cib + j) * 81 + tap * 9 + o]) : (ushort)0;
            uint4 pk;
            pk.x = vals[0] | ((unsigned)vals[1] << 16);
            pk.y = vals[2] | ((unsigned)vals[3] << 16);
            pk.z = vals[4] | ((unsigned)vals[5] << 16);
            pk.w = vals[6] | ((unsigned)vals[7] << 16);
            *(uint4*)(ws + (size_t)i * 16) = pk;
        }
    }
}

// ---------------- main kernel: G=2 v-adjacent output slabs per block ----------------
__global__ void __launch_bounds__(256, 3)
conv4d_main(const char* __restrict__ ws, const float* __restrict__ bias,
            float* __restrict__ out) {
    __shared__ __align__(16) char lds[2 * SLAB_B];   // 43264 B double buffer

    const int t = threadIdx.x, lane = t & 63, wvid = t >> 6;
    const int b = blockIdx.x;                        // 576 = 2n * 24u * 12 vpairs
    const int nb = b / 288, rem = b % 288;
    const int u = rem / 12, v0 = (rem % 12) * 2;

    const int n16 = lane & 15, g = lane >> 4;
    const int dh = n16 >> 2, dw = n16 & 3;
    const int half = g & 1, osel = g >> 1;

    int laneoff[5];
    #pragma unroll
    for (int s = 0; s < 5; ++s) {
        int o = 2 * s + osel; if (o > 8) o = 8;      // K-tail clamp (A is zero there)
        int kh = o / 3, kw = o % 3;
        laneoff[s] = swz(dh + kh, dw + kw, half);
    }
    const int wv_off = (wvid >> 1) * 9984 + (wvid & 1) * 384;  // 12-row / 12-col quadrant

    f32x4 acc0[9], acc1[9];
    #pragma unroll
    for (int i = 0; i < 9; ++i) { acc0[i] = (f32x4){0,0,0,0}; acc1[i] = (f32x4){0,0,0,0}; }

    // valid-slab mask: i = 4*(uu-u+1) + (vv-v0+1)
    unsigned mask = 0;
    #pragma unroll
    for (int i = 0; i < 12; ++i) {
        int uu = u + (i >> 2) - 1, vv = v0 + (i & 3) - 1;
        if (uu >= 0 && uu < S && vv >= 0 && vv < S) mask |= 1u << i;
    }

    const char* slabs = ws + WS_SLABS;
    #define SLAB_PTR(i_) (slabs + ((size_t)nb * PLANE + (u + ((i_) >> 2) - 1) * S + (v0 + ((i_) & 3) - 1)) * SLAB_B)

    #define STAGE(bufsel_, src_) do {                                              \
        const char* _s = (src_);                                                   \
        _Pragma("unroll")                                                          \
        for (int r2 = 0; r2 < 6; ++r2) {                                           \
            int chunk = r2 * 256 + t;                                              \
            if (r2 < 5 || t < 72)                                                  \
                __builtin_amdgcn_global_load_lds(                                  \
                    (const __attribute__((address_space(1))) unsigned int*)(_s + (size_t)chunk * 16), \
                    (__attribute__((address_space(3))) unsigned int*)(lds + (bufsel_) * SLAB_B + chunk * 16), \
                    16, 0, 0);                                                     \
        }                                                                          \
    } while (0)

    const bf16x8 zfr = {0,0,0,0,0,0,0,0};

    int cur = __ffs(mask) - 1;
    int bufsel = 0;
    STAGE(0, SLAB_PTR(cur));
    __syncthreads();

    while (1) {
        unsigned remm = mask >> (cur + 1);
        int nxt = remm ? (cur + 1 + __ffs(remm) - 1) : -1;
        if (nxt >= 0) STAGE(bufsel ^ 1, SLAB_PTR(nxt));   // overlaps compute below

        const int ku = cur >> 2, dv = (cur & 3) - 1;      // dv in -1..2
        const bool v0ok = dv <= 1, v1ok = dv >= 0;
        const char* ap0 = ws + (size_t)(ku * 3 + dv + 1) * 5120 + (size_t)lane * 16;
        const char* ap1 = ws + (size_t)(ku * 3 + dv) * 5120 + (size_t)lane * 16;
        bf16x8 afr0[5], afr1[5];
        #pragma unroll
        for (int s = 0; s < 5; ++s) {
            afr0[s] = v0ok ? *(const bf16x8*)(ap0 + s * 1024) : zfr;
            afr1[s] = v1ok ? *(const bf16x8*)(ap1 + s * 1024) : zfr;
        }

        const char* bp = lds + bufsel * SLAB_B + wv_off;
        #pragma unroll
        for (int ti = 0; ti < 9; ++ti) {
            const int timm = (ti / 3) * 3328 + (ti % 3) * 128;
            #pragma unroll
            for (int s = 0; s < 5; ++s) {
                bf16x8 bfr = *(const bf16x8*)(bp + timm + laneoff[s]);
                acc0[ti] = __builtin_amdgcn_mfma_f32_16x16x32_bf16(afr0[s], bfr, acc0[ti], 0, 0, 0);
                acc1[ti] = __builtin_amdgcn_mfma_f32_16x16x32_bf16(afr1[s], bfr, acc1[ti], 0, 0, 0);
            }
        }
        __syncthreads();   // drains prefetch + read/write fence
        if (nxt < 0) break;
        cur = nxt; bufsel ^= 1;
    }

    // epilogue: C col = lane&15 -> (dh,dw); row = g*4+r -> c_out ; two v-slabs
    float bv[4];
    #pragma unroll
    for (int r = 0; r < 4; ++r) bv[r] = bias[g * 4 + r];
    float* outp0 = out + (size_t)nb * 16 * CISTRIDE + (size_t)(u * S + v0) * PLANE;
    float* outp1 = outp0 + PLANE;
    #pragma unroll
    for (int ti = 0; ti < 9; ++ti) {
        int h0 = ((ti / 3) + (wvid >> 1) * 3) * 4;
        int w0 = ((ti % 3) + (wvid & 1) * 3) * 4;
        int pos = (h0 + dh) * S + (w0 + dw);
        #pragma unroll
        for (int r = 0; r < 4; ++r) {
            outp0[(size_t)(g * 4 + r) * CISTRIDE + pos] = acc0[ti][r] + bv[r];
            outp1[(size_t)(g * 4 + r) * CISTRIDE + pos] = acc1[ti][r] + bv[r];
        }
    }
}

extern "C" void kernel_launch(void* const* d_in, const int* in_sizes, int n_in,
                              void* d_out, int out_size, void* d_ws, size_t ws_size,
                              hipStream_t stream) {
    const float* in   = (const float*)d_in[0];
    const float* wgt  = (const float*)d_in[1];
    const float* bias = (const float*)d_in[2];
    float* out        = (float*)d_out;
    char* ws          = (char*)d_ws;

    pack_in<<<dim3(2 * PLANE), dim3(256), 0, stream>>>(in, wgt, ws);
    conv4d_main<<<dim3(576), dim3(256), 0, stream>>>(ws, bias, out);
}

// Round 6
// 85.032 us; speedup vs baseline: 7.5567x; 1.0470x over previous
//
#include <hip/hip_runtime.h>

#define S 24
#define PLANE 576
#define CISTRIDE 331776          // floats per (n,ci)
#define SLAB_B 21632             // 676 positions * 32 B
#define A_BYTES 46080            // 9 taps * 5 steps * 64 lanes * 16 B
#define WS_SLABS A_BYTES

typedef __attribute__((ext_vector_type(8))) short bf16x8;
typedef __attribute__((ext_vector_type(4))) float f32x4;

__device__ __forceinline__ ushort f2bf(float f) {   // round-to-nearest-even
    unsigned int u = __builtin_bit_cast(unsigned int, f);
    unsigned int r = u + 0x7fffu + ((u >> 16) & 1u);
    return (ushort)(r >> 16);
}

// slot swizzle: byte offset for (row,col,half) = ((row*26+col)*32 + half*16) ^ ((row&3)<<4)
__device__ __forceinline__ int swz(int row, int col, int half) {
    return (((row * 26 + col) * 32) + half * 16) ^ ((row & 3) << 4);
}

// ---------------- prepass: pack input slabs via LDS transpose (+ weights from block 0) ----
__global__ void __launch_bounds__(256)
pack_in(const float* __restrict__ in, const float* __restrict__ wgt, char* __restrict__ ws) {
    __shared__ unsigned lds_t[16][288];   // [ci][pos-pair] packed bf16x2 (two positions, one ci)

    const int b = blockIdx.x;             // 1152 slabs
    const int nb = b / PLANE, uv = b % PLANE;
    const float* src = in + (size_t)nb * 16 * CISTRIDE + (size_t)uv * PLANE;
    char* dst = ws + WS_SLABS + (size_t)b * SLAB_B;
    const int t = threadIdx.x;

    // phase 1: coalesced global float4 reads, bf16-pack, LDS b64 writes
    #pragma unroll
    for (int i = 0; i < 9; ++i) {
        int flat = i * 256 + t;           // 0..2303 float4 chunks
        int ci = flat / 144, q4 = flat % 144;
        float4 f = *(const float4*)(src + (size_t)ci * CISTRIDE + 4 * q4);
        uint2 pk;
        pk.x = (unsigned)f2bf(f.x) | ((unsigned)f2bf(f.y) << 16);
        pk.y = (unsigned)f2bf(f.z) | ((unsigned)f2bf(f.w) << 16);
        *(uint2*)&lds_t[ci][2 * q4] = pk;
    }
    __syncthreads();

    // phase 2: assemble swizzled 16B chunks, linear coalesced global writes
    #pragma unroll
    for (int i = 0; i < 6; ++i) {
        int c = i * 256 + t;              // chunk index 0..1351
        if (c < 1352) {
            int k = c >> 2;
            int row = k / 13;             // pairs never cross a row (26 even)
            int pos2 = c ^ (row & 3);
            int pos = pos2 >> 1, h = pos2 & 1;
            int col = pos - row * 26;
            uint4 o = make_uint4(0, 0, 0, 0);
            if (row >= 1 && row <= 24 && col >= 1 && col <= 24) {
                int q = (row - 1) * 24 + (col - 1);
                int q2 = q >> 1, odd = q & 1;
                #pragma unroll
                for (int kk = 0; kk < 4; ++kk) {
                    unsigned a = lds_t[8 * h + 2 * kk][q2];
                    unsigned bb = lds_t[8 * h + 2 * kk + 1][q2];
                    unsigned val = odd ? ((a >> 16) | (bb & 0xffff0000u))
                                       : ((a & 0xffffu) | (bb << 16));
                    ((unsigned*)&o)[kk] = val;
                }
            }
            *(uint4*)(dst + (size_t)c * 16) = o;
        }
    }

    if (b == 0) {                        // weight A-fragments -> ws[0..A_BYTES)
        for (int i = t; i < 2880; i += 256) {
            int step = i >> 6;           // 0..44
            int tap = step / 5, s = step % 5;
            int lane = i & 63;
            int co = lane & 15, gA = lane >> 4;
            int o = 2 * s + (gA >> 1);
            int cib = (gA & 1) * 8;
            ushort vals[8];
            #pragma unroll
            for (int j = 0; j < 8; ++j)
                vals[j] = (o <= 8) ? f2bf(wgt[co * 1296 + (cib + j) * 81 + tap * 9 + o]) : (ushort)0;
            uint4 pk;
            pk.x = vals[0] | ((unsigned)vals[1] << 16);
            pk.y = vals[2] | ((unsigned)vals[3] << 16);
            pk.z = vals[4] | ((unsigned)vals[5] << 16);
            pk.w = vals[6] | ((unsigned)vals[7] << 16);
            *(uint4*)(ws + (size_t)i * 16) = pk;
        }
    }
}

// ---------------- main kernel: G=2 v-adjacent output slabs per block ----------------
__global__ void __launch_bounds__(256, 3)
conv4d_main(const char* __restrict__ ws, const float* __restrict__ bias,
            float* __restrict__ out) {
    __shared__ __align__(16) char lds[2 * SLAB_B];   // 43264 B double buffer

    const int t = threadIdx.x, lane = t & 63, wvid = t >> 6;
    // XCD-chunked bijective swizzle: 576 work ids, 8 XCDs x 72 contiguous
    const int braw = blockIdx.x;
    const int b = (braw & 7) * 72 + (braw >> 3);
    const int nb = b / 288, rem = b % 288;
    const int u = rem / 12, v0 = (rem % 12) * 2;

    const int n16 = lane & 15, g = lane >> 4;
    const int dh = n16 >> 2, dw = n16 & 3;
    const int half = g & 1, osel = g >> 1;

    int laneoff[5];
    #pragma unroll
    for (int s = 0; s < 5; ++s) {
        int o = 2 * s + osel; if (o > 8) o = 8;      // K-tail clamp (A is zero there)
        int kh = o / 3, kw = o % 3;
        laneoff[s] = swz(dh + kh, dw + kw, half);
    }
    const int wv_off = (wvid >> 1) * 9984 + (wvid & 1) * 384;  // 12-row / 12-col quadrant

    f32x4 acc0[9], acc1[9];
    #pragma unroll
    for (int i = 0; i < 9; ++i) { acc0[i] = (f32x4){0,0,0,0}; acc1[i] = (f32x4){0,0,0,0}; }

    // valid-slab mask: i = 4*(uu-u+1) + (vv-v0+1)
    unsigned mask = 0;
    #pragma unroll
    for (int i = 0; i < 12; ++i) {
        int uu = u + (i >> 2) - 1, vv = v0 + (i & 3) - 1;
        if (uu >= 0 && uu < S && vv >= 0 && vv < S) mask |= 1u << i;
    }

    const char* slabs = ws + WS_SLABS;
    #define SLAB_PTR(i_) (slabs + ((size_t)nb * PLANE + (u + ((i_) >> 2) - 1) * S + (v0 + ((i_) & 3) - 1)) * SLAB_B)

    #define STAGE(bufsel_, src_) do {                                              \
        const char* _s = (src_);                                                   \
        _Pragma("unroll")                                                          \
        for (int r2 = 0; r2 < 6; ++r2) {                                           \
            int chunk = r2 * 256 + t;                                              \
            if (r2 < 5 || t < 72)                                                  \
                __builtin_amdgcn_global_load_lds(                                  \
                    (const __attribute__((address_space(1))) unsigned int*)(_s + (size_t)chunk * 16), \
                    (__attribute__((address_space(3))) unsigned int*)(lds + (bufsel_) * SLAB_B + chunk * 16), \
                    16, 0, 0);                                                     \
        }                                                                          \
    } while (0)

    const bf16x8 zfr = {0,0,0,0,0,0,0,0};

    int cur = __ffs(mask) - 1;
    int bufsel = 0;
    STAGE(0, SLAB_PTR(cur));
    __syncthreads();

    while (1) {
        unsigned remm = mask >> (cur + 1);
        int nxt = remm ? (cur + 1 + __ffs(remm) - 1) : -1;
        if (nxt >= 0) STAGE(bufsel ^ 1, SLAB_PTR(nxt));   // overlaps compute below

        const int ku = cur >> 2, dv = (cur & 3) - 1;      // dv in -1..2
        const bool v0ok = dv <= 1, v1ok = dv >= 0;
        const char* ap0 = ws + (size_t)(ku * 3 + dv + 1) * 5120 + (size_t)lane * 16;
        const char* ap1 = ws + (size_t)(ku * 3 + dv) * 5120 + (size_t)lane * 16;
        bf16x8 afr0[5], afr1[5];
        #pragma unroll
        for (int s = 0; s < 5; ++s) {
            afr0[s] = v0ok ? *(const bf16x8*)(ap0 + s * 1024) : zfr;
            afr1[s] = v1ok ? *(const bf16x8*)(ap1 + s * 1024) : zfr;
        }

        const char* bp = lds + bufsel * SLAB_B + wv_off;
        #pragma unroll
        for (int ti = 0; ti < 9; ++ti) {
            const int timm = (ti / 3) * 3328 + (ti % 3) * 128;
            #pragma unroll
            for (int s = 0; s < 5; ++s) {
                bf16x8 bfr = *(const bf16x8*)(bp + timm + laneoff[s]);
                acc0[ti] = __builtin_amdgcn_mfma_f32_16x16x32_bf16(afr0[s], bfr, acc0[ti], 0, 0, 0);
                acc1[ti] = __builtin_amdgcn_mfma_f32_16x16x32_bf16(afr1[s], bfr, acc1[ti], 0, 0, 0);
            }
        }
        __syncthreads();   // drains prefetch + read/write fence
        if (nxt < 0) break;
        cur = nxt; bufsel ^= 1;
    }

    // epilogue: C col = lane&15 -> (dh,dw); row = g*4+r -> c_out ; two v-slabs
    float bv[4];
    #pragma unroll
    for (int r = 0; r < 4; ++r) bv[r] = bias[g * 4 + r];
    float* outp0 = out + (size_t)nb * 16 * CISTRIDE + (size_t)(u * S + v0) * PLANE;
    float* outp1 = outp0 + PLANE;
    #pragma unroll
    for (int ti = 0; ti < 9; ++ti) {
        int h0 = ((ti / 3) + (wvid >> 1) * 3) * 4;
        int w0 = ((ti % 3) + (wvid & 1) * 3) * 4;
        int pos = (h0 + dh) * S + (w0 + dw);
        #pragma unroll
        for (int r = 0; r < 4; ++r) {
            outp0[(size_t)(g * 4 + r) * CISTRIDE + pos] = acc0[ti][r] + bv[r];
            outp1[(size_t)(g * 4 + r) * CISTRIDE + pos] = acc1[ti][r] + bv[r];
        }
    }
}

extern "C" void kernel_launch(void* const* d_in, const int* in_sizes, int n_in,
                              void* d_out, int out_size, void* d_ws, size_t ws_size,
                              hipStream_t stream) {
    const float* in   = (const float*)d_in[0];
    const float* wgt  = (const float*)d_in[1];
    const float* bias = (const float*)d_in[2];
    float* out        = (float*)d_out;
    char* ws          = (char*)d_ws;

    pack_in<<<dim3(2 * PLANE), dim3(256), 0, stream>>>(in, wgt, ws);
    conv4d_main<<<dim3(576), dim3(256), 0, stream>>>(ws, bias, out);
}